// Round 7
// baseline (532.787 us; speedup 1.0000x reference)
//
#include <hip/hip_runtime.h>
#include <hip/hip_bf16.h>
#include <stdint.h>

// ---------------------------------------------------------------------------
// Self-attention forward, B=4 S=4096 D=1024, fp32 in -> f32 out.
// GEMM: 256x256 tile, BK=64, FOUR waves (2x2, 128x128/wave) using
// mfma_f32_32x32x16_bf16. Rationale: LDS read traffic = 2K(bM+aN) bytes is
// minimized by the 2x2 wave grid (128 KB/K-tile vs 192 KB at 2x4), and the
// 32x32 MFMA runs at 2495 vs 2075 TF. dbuf LDS, one vmcnt(0)+barrier per
// K-tile, XOR slot swizzle, setprio, XCD-chunked block swizzle.
// ---------------------------------------------------------------------------

typedef __attribute__((ext_vector_type(8))) short bf16x8;
typedef __attribute__((ext_vector_type(16))) float f32x16;

static __device__ __forceinline__ unsigned short f2b(float f) {
  union { float f; unsigned u; } x; x.f = f;
  unsigned u = x.u;
  u += 0x7fffu + ((u >> 16) & 1u);      // RNE
  return (unsigned short)(u >> 16);
}
static __device__ __forceinline__ float b2f(unsigned short s) {
  union { unsigned u; float f; } x; x.u = ((unsigned)s) << 16;
  return x.f;
}

// async global->LDS, 16B per lane. LDS dest: wave-uniform base + lane*16.
static __device__ __forceinline__ void gl_lds16(const void* g, void* l) {
  __builtin_amdgcn_global_load_lds(
      (const __attribute__((address_space(1))) void*)(uintptr_t)(g),
      (__attribute__((address_space(3))) void*)(uint32_t)(uintptr_t)(l),
      16, 0, 0);
}

// ---------------------------------------------------------------------------
__global__ void convert_x(const float* __restrict__ in,
                          unsigned short* __restrict__ out, int n8) {
  int i = blockIdx.x * blockDim.x + threadIdx.x;
  if (i >= n8) return;
  const float4* p = (const float4*)in + (size_t)i * 2;
  float4 a = p[0], b = p[1];
  bf16x8 o;
  o[0] = (short)f2b(a.x); o[1] = (short)f2b(a.y);
  o[2] = (short)f2b(a.z); o[3] = (short)f2b(a.w);
  o[4] = (short)f2b(b.x); o[5] = (short)f2b(b.y);
  o[6] = (short)f2b(b.z); o[7] = (short)f2b(b.w);
  ((bf16x8*)out)[i] = o;
}

__global__ void transpose_w(const float* __restrict__ in,
                            unsigned short* __restrict__ out) {
  __shared__ float tile[32][33];
  const int tx = threadIdx.x;
  const int x = blockIdx.x * 32 + tx;
  const int y0 = blockIdx.y * 32;
  for (int j = threadIdx.y; j < 32; j += 8)
    tile[j][tx] = in[(size_t)(y0 + j) * 1024 + x];
  __syncthreads();
  const int ox = blockIdx.y * 32 + tx;
  const int oy0 = blockIdx.x * 32;
  for (int j = threadIdx.y; j < 32; j += 8)
    out[(size_t)(oy0 + j) * 1024 + ox] = f2b(tile[tx][j]);
}

// ---------------------------------------------------------------------------
// 256x256 NT GEMM, BK=64, 256 threads (4 waves, 2x2), 32x32x16 MFMA.
// C[m][n] = alpha * sum_k A[m][k]*B[n][k] (+bias). z-batched via strides.
// Requires M%256==0, N%256==0, K%64==0, K/64>=2.
//
// LDS tile [256 rows][64 k] bf16 = 128 B/row = 8 granules of 16 B.
// Granule swizzle: lds_slot = glob_granule ^ (row&7)  (bijective per row).
// Stage side: gl_lds writes linearly; thread t's GLOBAL source is
// pre-permuted (granule (t&7)^((t>>3)&7)). Read side applies the same XOR.
// Read pattern (32x32 frag, lanes 0..63: row=l&31, khalf=l>>5): slots hit
// uniformly 8 lanes/slot => conflict-free.
// ---------------------------------------------------------------------------
template <int OUTF>
__global__ __launch_bounds__(256)
void gemm256(const unsigned short* __restrict__ A, long lda, long sAz,
             const unsigned short* __restrict__ B, long ldb, long sBz,
             void* __restrict__ Cv, long ldc, long sCz,
             const float* __restrict__ bias, int bias_mode,
             int K, float alpha) {
  __shared__ __align__(16) unsigned short As[2][256 * 64];
  __shared__ __align__(16) unsigned short Bs[2][256 * 64];

  // XCD-chunked block swizzle (T1)
  const unsigned gx = gridDim.x, gy = gridDim.y;
  const unsigned nwg = gx * gy * gridDim.z;
  const unsigned hwid = (blockIdx.z * gy + blockIdx.y) * gx + blockIdx.x;
  unsigned tile = hwid;
  if ((nwg & 7u) == 0u) tile = (hwid & 7u) * (nwg >> 3) + (hwid >> 3);
  const unsigned bxi = tile % gx;
  const unsigned byi = (tile / gx) % gy;
  const unsigned bzi = tile / (gx * gy);

  const int t = threadIdx.x;
  const int wid = t >> 6, lane = t & 63;
  const int wm = wid >> 1, wn = wid & 1;       // 2x2 wave grid, 128x128/wave
  const int fr = lane & 31;                    // fragment row (M or N)
  const int fh = lane >> 5;                    // K-half within 16-K step
  const long bm = (long)byi * 256;
  const long bn = (long)bxi * 256;
  const unsigned short* Ab = A + (size_t)bzi * sAz;
  const unsigned short* Bb = B + (size_t)bzi * sBz;

  // staging: one gl_lds call = 256 threads x 16B = 4KB = 32 rows x 64 cols.
  // global source granule pre-permuted: (t&7) ^ (row&7), row = t>>3 (mod 8).
  const int srow = t >> 3;                              // 0..31 within call
  const int scol = 8 * ((t & 7) ^ ((t >> 3) & 7));      // permuted granule
  const unsigned short* AgS = Ab + (bm + srow) * lda + scol;
  const unsigned short* BgS = Bb + (bn + srow) * ldb + scol;
  const int dstw = wid * 512;   // wave base within a 4KB call region (shorts)

  const int NT = K >> 6;
  f32x16 acc[4][4] = {};

  // stage all 16 calls (A 8 + B 8) for K-tile kt into buffer buf
  auto stage_tile = [&](int kt, int buf) {
#pragma unroll
    for (int h = 0; h < 8; ++h)
      gl_lds16(AgS + (size_t)(h * 32) * lda + (size_t)kt * 64,
               &As[buf][h * 2048 + dstw]);
#pragma unroll
    for (int h = 0; h < 8; ++h)
      gl_lds16(BgS + (size_t)(h * 32) * ldb + (size_t)kt * 64,
               &Bs[buf][h * 2048 + dstw]);
  };

  // swizzled fragment reads (ks = K-step 0..3)
  auto rdA = [&](int buf, int i, int ks) {
    const int row = wm * 128 + i * 32 + fr;
    const int sl = ((ks * 2 + fh) ^ (row & 7)) << 4;
    return *(const bf16x8*)((const char*)&As[buf][0] + row * 128 + sl);
  };
  auto rdB = [&](int buf, int j, int ks) {
    const int row = wn * 128 + j * 32 + fr;
    const int sl = ((ks * 2 + fh) ^ (row & 7)) << 4;
    return *(const bf16x8*)((const char*)&Bs[buf][0] + row * 128 + sl);
  };

  // prologue
  stage_tile(0, 0);
  asm volatile("s_waitcnt vmcnt(0)" ::: "memory");
  asm volatile("s_barrier" ::: "memory");

  for (int tt = 0; tt < NT; ++tt) {
    const int cb = tt & 1, nb = (tt + 1) & 1;
    if (tt + 1 < NT) stage_tile(tt + 1, nb);

    bf16x8 a[4], b[4], an[4], bn[4];
#pragma unroll
    for (int i = 0; i < 4; ++i) a[i] = rdA(cb, i, 0);
#pragma unroll
    for (int j = 0; j < 4; ++j) b[j] = rdB(cb, j, 0);

    __builtin_amdgcn_s_setprio(1);
#pragma unroll
    for (int ks = 0; ks < 4; ++ks) {
      if (ks < 3) {
#pragma unroll
        for (int i = 0; i < 4; ++i) an[i] = rdA(cb, i, ks + 1);
#pragma unroll
        for (int j = 0; j < 4; ++j) bn[j] = rdB(cb, j, ks + 1);
      }
#pragma unroll
      for (int i = 0; i < 4; ++i)
#pragma unroll
        for (int j = 0; j < 4; ++j)
          acc[i][j] = __builtin_amdgcn_mfma_f32_32x32x16_bf16(
              a[i], b[j], acc[i][j], 0, 0, 0);
      if (ks < 3) {
#pragma unroll
        for (int i = 0; i < 4; ++i) { a[i] = an[i]; b[i] = bn[i]; }
      }
    }
    __builtin_amdgcn_s_setprio(0);

    asm volatile("s_waitcnt vmcnt(0)" ::: "memory");
    asm volatile("s_barrier" ::: "memory");
  }

  // epilogue: 32x32 C/D layout col=lane&31, row=(r&3)+8*(r>>2)+4*(lane>>5)
  char* Cb = (char*)Cv + (size_t)bzi * sCz * (OUTF ? 4 : 2);
  const long crow0 = bm + wm * 128;
  const long ccol0 = bn + wn * 128;
#pragma unroll
  for (int i = 0; i < 4; ++i) {
#pragma unroll
    for (int j = 0; j < 4; ++j) {
      const long col = ccol0 + j * 32 + fr;
      float badd_c = (bias_mode == 1) ? bias[col] : 0.0f;
#pragma unroll
      for (int r = 0; r < 16; ++r) {
        const long row = crow0 + i * 32 + (r & 3) + 8 * (r >> 2) + 4 * fh;
        float v = acc[i][j][r] * alpha + badd_c;
        if (bias_mode == 2) v += bias[row];
        if (OUTF)
          ((float*)Cb)[row * ldc + col] = v;
        else
          ((unsigned short*)Cb)[row * ldc + col] = f2b(v);
      }
    }
  }
}

// ---------------------------------------------------------------------------
// In-place row softmax over bf16 rows of length 4096. One block (256thr)/row.
// ---------------------------------------------------------------------------
__global__ __launch_bounds__(256)
void softmax_rows(unsigned short* __restrict__ S) {
  const int t = threadIdx.x;
  unsigned short* row = S + (size_t)blockIdx.x * 4096;
  const bf16x8* p = (const bf16x8*)row;
  bf16x8 u0 = p[t * 2], u1 = p[t * 2 + 1];

  float v[16];
  float m = -1e30f;
#pragma unroll
  for (int j = 0; j < 8; j++) { v[j] = b2f((unsigned short)u0[j]); }
#pragma unroll
  for (int j = 0; j < 8; j++) { v[8 + j] = b2f((unsigned short)u1[j]); }
#pragma unroll
  for (int j = 0; j < 16; j++) m = fmaxf(m, v[j]);

#pragma unroll
  for (int off = 32; off > 0; off >>= 1) m = fmaxf(m, __shfl_xor(m, off));
  __shared__ float redm[4];
  if ((t & 63) == 0) redm[t >> 6] = m;
  __syncthreads();
  m = fmaxf(fmaxf(redm[0], redm[1]), fmaxf(redm[2], redm[3]));

  float s = 0.0f;
#pragma unroll
  for (int j = 0; j < 16; j++) { v[j] = __expf(v[j] - m); s += v[j]; }
#pragma unroll
  for (int off = 32; off > 0; off >>= 1) s += __shfl_xor(s, off);
  __shared__ float reds[4];
  if ((t & 63) == 0) reds[t >> 6] = s;
  __syncthreads();
  s = reds[0] + reds[1] + reds[2] + reds[3];
  const float inv = 1.0f / s;

  bf16x8 o0, o1;
#pragma unroll
  for (int j = 0; j < 8; j++) o0[j] = (short)f2b(v[j] * inv);
#pragma unroll
  for (int j = 0; j < 8; j++) o1[j] = (short)f2b(v[8 + j] * inv);
  bf16x8* q = (bf16x8*)row;
  q[t * 2] = o0;
  q[t * 2 + 1] = o1;
}

// ---------------------------------------------------------------------------
extern "C" void kernel_launch(void* const* d_in, const int* in_sizes, int n_in,
                              void* d_out, int out_size, void* d_ws,
                              size_t ws_size, hipStream_t stream) {
  const float* x  = (const float*)d_in[0];
  const float* Wq = (const float*)d_in[1];
  const float* bq = (const float*)d_in[2];
  const float* Wk = (const float*)d_in[3];
  const float* bk = (const float*)d_in[4];
  const float* Wv = (const float*)d_in[5];
  const float* bv = (const float*)d_in[6];
  float* out = (float*)d_out;

  const int Bb = 4, S = 4096, D = 1024;
  const long BS = (long)Bb * S;                 // 16384
  const size_t MiB = 1u << 20;

  char* base = (char*)d_ws;
  unsigned short* Wqt = (unsigned short*)(base);              // 2 MiB
  unsigned short* Wkt = (unsigned short*)(base + 2 * MiB);    // 2
  unsigned short* Wvt = (unsigned short*)(base + 4 * MiB);    // 2
  unsigned short* Qb  = (unsigned short*)(base + 6 * MiB);    // 32
  unsigned short* Kb  = (unsigned short*)(base + 38 * MiB);   // 32
  unsigned short* Vt  = (unsigned short*)(base + 70 * MiB);   // 32  [D][BS]
  unsigned short* xb  = (unsigned short*)(base + 102 * MiB);  // 32 (dies early)
  unsigned short* Sb  = xb;  // scores region overlaps dead xb
  const bool batched = ws_size >= (size_t)(102 + 128) * MiB;  // 4-batch scores

  // 1. x -> bf16
  const int n8 = (int)(BS * D / 8);
  convert_x<<<n8 / 256, 256, 0, stream>>>(x, xb, n8);

  // 2. W -> W^T bf16
  dim3 tb(32, 8), tg(32, 32);
  transpose_w<<<tg, tb, 0, stream>>>(Wq, Wqt);
  transpose_w<<<tg, tb, 0, stream>>>(Wk, Wkt);
  transpose_w<<<tg, tb, 0, stream>>>(Wv, Wvt);

  // 3. projections
  gemm256<0><<<dim3(D / 256, BS / 256, 1), 256, 0, stream>>>(
      xb, D, 0, Wqt, D, 0, Qb, D, 0, bq, 1, D, 1.0f);
  gemm256<0><<<dim3(D / 256, BS / 256, 1), 256, 0, stream>>>(
      xb, D, 0, Wkt, D, 0, Kb, D, 0, bk, 1, D, 1.0f);
  gemm256<0><<<dim3(BS / 256, D / 256, 1), 256, 0, stream>>>(
      Wvt, D, 0, xb, D, 0, Vt, BS, 0, bv, 2, D, 1.0f);

  // 4. attention
  const float scale = 0.03125f;  // 1/sqrt(1024)
  if (batched) {
    gemm256<0><<<dim3(S / 256, S / 256, Bb), 256, 0, stream>>>(
        Qb, D, (long)S * D, Kb, D, (long)S * D, Sb, S, (long)S * S,
        nullptr, 0, D, scale);
    softmax_rows<<<Bb * S, 256, 0, stream>>>(Sb);
    gemm256<1><<<dim3(D / 256, S / 256, Bb), 256, 0, stream>>>(
        Sb, S, (long)S * S, Vt, BS, (long)S, out, D, (long)S * D,
        nullptr, 0, S, 1.0f);
  } else {
    for (int b = 0; b < Bb; b++) {
      const unsigned short* Qp = Qb + (long)b * S * D;
      const unsigned short* Kp = Kb + (long)b * S * D;
      gemm256<0><<<dim3(S / 256, S / 256, 1), 256, 0, stream>>>(
          Qp, D, 0, Kp, D, 0, Sb, S, 0, nullptr, 0, D, scale);
      softmax_rows<<<S, 256, 0, stream>>>(Sb);
      gemm256<1><<<dim3(D / 256, S / 256, 1), 256, 0, stream>>>(
          Sb, S, 0, Vt + (long)b * S, BS, 0, out + (long)b * S * D, D, 0,
          nullptr, 0, S, 1.0f);
    }
  }
}

// Round 9
// 460.369 us; speedup vs baseline: 1.1573x; 1.1573x over previous
//
#include <hip/hip_runtime.h>
#include <hip/hip_bf16.h>
#include <stdint.h>

// ---------------------------------------------------------------------------
// Self-attention forward, B=4 S=4096 D=1024, fp32 in -> f32 out.
// GEMM: 256x256 tile, BK=64, 8 waves (2x4), 16x16x32 MFMA, dbuf LDS.
// m201-style 8-phase schedule: per K-tile 4 phases, each
//   {ds_reads; stage 1 half-tile; bar; lgkmcnt(0)+sched_barrier; 16 MFMA; bar}
// with counted vmcnt(4) only at tile boundaries and 2-tile-deep staging
// (3-6 phases of slack per half-tile). XOR-swizzled LDS (0-conflict, R4 map),
// XCD-chunked block swizzle.
// ---------------------------------------------------------------------------

typedef __attribute__((ext_vector_type(8))) short bf16x8;
typedef __attribute__((ext_vector_type(4))) float f32x4;

static __device__ __forceinline__ unsigned short f2b(float f) {
  union { float f; unsigned u; } x; x.f = f;
  unsigned u = x.u;
  u += 0x7fffu + ((u >> 16) & 1u);      // RNE
  return (unsigned short)(u >> 16);
}
static __device__ __forceinline__ float b2f(unsigned short s) {
  union { unsigned u; float f; } x; x.u = ((unsigned)s) << 16;
  return x.f;
}

// async global->LDS, 16B per lane. LDS dest: wave-uniform base + lane*16.
static __device__ __forceinline__ void gl_lds16(const void* g, void* l) {
  __builtin_amdgcn_global_load_lds(
      (const __attribute__((address_space(1))) void*)(uintptr_t)(g),
      (__attribute__((address_space(3))) void*)(uint32_t)(uintptr_t)(l),
      16, 0, 0);
}

// ---------------------------------------------------------------------------
__global__ void convert_x(const float* __restrict__ in,
                          unsigned short* __restrict__ out, int n8) {
  int i = blockIdx.x * blockDim.x + threadIdx.x;
  if (i >= n8) return;
  const float4* p = (const float4*)in + (size_t)i * 2;
  float4 a = p[0], b = p[1];
  bf16x8 o;
  o[0] = (short)f2b(a.x); o[1] = (short)f2b(a.y);
  o[2] = (short)f2b(a.z); o[3] = (short)f2b(a.w);
  o[4] = (short)f2b(b.x); o[5] = (short)f2b(b.y);
  o[6] = (short)f2b(b.z); o[7] = (short)f2b(b.w);
  ((bf16x8*)out)[i] = o;
}

__global__ void transpose_w(const float* __restrict__ in,
                            unsigned short* __restrict__ out) {
  __shared__ float tile[32][33];
  const int tx = threadIdx.x;
  const int x = blockIdx.x * 32 + tx;
  const int y0 = blockIdx.y * 32;
  for (int j = threadIdx.y; j < 32; j += 8)
    tile[j][tx] = in[(size_t)(y0 + j) * 1024 + x];
  __syncthreads();
  const int ox = blockIdx.y * 32 + tx;
  const int oy0 = blockIdx.x * 32;
  for (int j = threadIdx.y; j < 32; j += 8)
    out[(size_t)(oy0 + j) * 1024 + ox] = f2b(tile[tx][j]);
}

// ---------------------------------------------------------------------------
// 256x256 NT GEMM, BK=64, 512 threads (8 waves, 2x4), dbuf LDS, 8-phase.
// C[m][n] = alpha * sum_k A[m][k]*B[n][k] (+bias). z-batched via strides.
// Requires M%256==0, N%256==0, K%128==0 (NT even), K>=128.
// ---------------------------------------------------------------------------
#define MFMA16(a, b, c) __builtin_amdgcn_mfma_f32_16x16x32_bf16(a, b, c, 0, 0, 0)

template <int OUTF>
__global__ __launch_bounds__(512, 2)
void gemm256(const unsigned short* __restrict__ A, long lda, long sAz,
             const unsigned short* __restrict__ B, long ldb, long sBz,
             void* __restrict__ Cv, long ldc, long sCz,
             const float* __restrict__ bias, int bias_mode,
             int K, float alpha) {
  __shared__ __align__(16) unsigned short As[2][256 * 64];
  __shared__ __align__(16) unsigned short Bs[2][256 * 64];

  // XCD-chunked block swizzle (T1)
  const unsigned gx = gridDim.x, gy = gridDim.y;
  const unsigned nwg = gx * gy * gridDim.z;
  const unsigned hwid = (blockIdx.z * gy + blockIdx.y) * gx + blockIdx.x;
  unsigned tileid = hwid;
  if ((nwg & 7u) == 0u) tileid = (hwid & 7u) * (nwg >> 3) + (hwid >> 3);
  const unsigned bxi = tileid % gx;
  const unsigned byi = (tileid / gx) % gy;
  const unsigned bzi = tileid / (gx * gy);

  const int t = threadIdx.x;
  const int wid = t >> 6, lane = t & 63;
  const int wm = wid >> 2, wn = wid & 3;      // 2x4 wave grid
  const int fr = lane & 15, fq = lane >> 4;
  const long bm = (long)byi * 256;
  const long bn = (long)bxi * 256;
  const unsigned short* Ab = A + (size_t)bzi * sAz;
  const unsigned short* Bb = B + (size_t)bzi * sBz;

  // staging: one gl_lds call = 512 lanes x 16B = 64 rows x 64 cols bf16.
  // pre-swizzled global source (rule #21): granule ^= row&7 (R4 map, 0-conf).
  const int sr = t >> 3;                       // 0..63 row within a call
  const int scol = 8 * ((t & 7) ^ (sr & 7));   // permuted granule (elements)
  const unsigned short* AgS = Ab + (bm + sr) * lda + scol;
  const unsigned short* BgS = Bb + (bn + sr) * ldb + scol;
  const int ldsw = wid * 512;                  // wave chunk base (shorts)

  const int NT = K >> 6;                       // even
  f32x4 acc[8][4] = {};

  // stage one half-tile (128 rows x 64 K) = 2 gl_lds calls
  auto SH = [&](const unsigned short* GS, long ld, int kt, int h,
                unsigned short* dstbuf) {
    const unsigned short* s = GS + (size_t)(h * 128) * ld + (size_t)kt * 64;
    gl_lds16(s, dstbuf + h * 128 * 64 + ldsw);
    gl_lds16(s + (size_t)64 * ld, dstbuf + (h * 128 + 64) * 64 + ldsw);
  };

  // swizzled ds_read: row-major [256][64] bf16, byte ^= (row&7)<<4
  auto rdA = [&](int buf, int m, int kh) {
    const int row = wm * 128 + m * 16 + fr;
    const int inb = (kh * 64 + fq * 16) ^ ((fr & 7) << 4);
    return *(const bf16x8*)((const char*)&As[buf][0] + row * 128 + inb);
  };
  auto rdB = [&](int buf, int j, int kh) {
    const int row = wn * 64 + j * 16 + fr;
    const int inb = (kh * 64 + fq * 16) ^ ((fr & 7) << 4);
    return *(const bf16x8*)((const char*)&Bs[buf][0] + row * 128 + inb);
  };

// one phase: reads -> stage -> bar -> lgkm0 -> 16 MFMA -> [wait] -> bar
#define PHASE(CB, P, STAGES, WAITS)                                           \
  {                                                                           \
    if ((P) == 0) {                                                           \
      _Pragma("unroll") for (int j = 0; j < 4; ++j) {                         \
        bfr[j][0] = rdB(CB, j, 0);                                            \
        bfr[j][1] = rdB(CB, j, 1);                                            \
      }                                                                       \
    }                                                                         \
    bf16x8 a00 = rdA(CB, 2 * (P), 0), a01 = rdA(CB, 2 * (P), 1);              \
    bf16x8 a10 = rdA(CB, 2 * (P) + 1, 0), a11 = rdA(CB, 2 * (P) + 1, 1);      \
    STAGES;                                                                   \
    if ((P) == 0) asm volatile("s_waitcnt lgkmcnt(8)" ::: "memory");          \
    __builtin_amdgcn_s_barrier();                                             \
    asm volatile("s_waitcnt lgkmcnt(0)" ::: "memory");                        \
    __builtin_amdgcn_sched_barrier(0);                                        \
    __builtin_amdgcn_s_setprio(1);                                            \
    _Pragma("unroll") for (int j = 0; j < 4; ++j) {                           \
      acc[2 * (P)][j] = MFMA16(a00, bfr[j][0], acc[2 * (P)][j]);              \
      acc[2 * (P)][j] = MFMA16(a01, bfr[j][1], acc[2 * (P)][j]);              \
      acc[2 * (P) + 1][j] = MFMA16(a10, bfr[j][0], acc[2 * (P) + 1][j]);      \
      acc[2 * (P) + 1][j] = MFMA16(a11, bfr[j][1], acc[2 * (P) + 1][j]);      \
    }                                                                         \
    __builtin_amdgcn_s_setprio(0);                                            \
    WAITS;                                                                    \
    __builtin_amdgcn_s_barrier();                                             \
  }

  // prologue: A(0),B(0),B(1) staged (12 loads), full drain, sync.
  SH(AgS, lda, 0, 0, &As[0][0]);
  SH(AgS, lda, 0, 1, &As[0][0]);
  SH(BgS, ldb, 0, 0, &Bs[0][0]);
  SH(BgS, ldb, 0, 1, &Bs[0][0]);
  if (1 < NT) {
    SH(BgS, ldb, 1, 0, &Bs[1][0]);
    SH(BgS, ldb, 1, 1, &Bs[1][0]);
  }
  asm volatile("s_waitcnt vmcnt(0)" ::: "memory");
  __builtin_amdgcn_s_barrier();

  for (int it = 0; it < (NT >> 1); ++it) {
    const int T = 2 * it;
    {  // tile a = T (buf 0)
      bf16x8 bfr[4][2];
      PHASE(0, 0, { if (T + 1 < NT) SH(AgS, lda, T + 1, 0, &As[1][0]); }, {});
      PHASE(0, 1, {
        if (T + 1 < NT) SH(AgS, lda, T + 1, 1, &As[1][0]);
        if (T + 2 < NT) SH(BgS, ldb, T + 2, 0, &Bs[0][0]);
      }, {});
      PHASE(0, 2, { if (T + 2 < NT) SH(BgS, ldb, T + 2, 1, &Bs[0][0]); }, {});
      PHASE(0, 3, {}, {
        if (T + 2 < NT)
          asm volatile("s_waitcnt vmcnt(4)" ::: "memory");
        else
          asm volatile("s_waitcnt vmcnt(0)" ::: "memory");
      });
    }
    {  // tile b = T+1 (buf 1)
      bf16x8 bfr[4][2];
      PHASE(1, 0, { if (T + 2 < NT) SH(AgS, lda, T + 2, 0, &As[0][0]); }, {});
      PHASE(1, 1, { if (T + 2 < NT) SH(AgS, lda, T + 2, 1, &As[0][0]); }, {});
      PHASE(1, 2, { if (T + 3 < NT) SH(BgS, ldb, T + 3, 0, &Bs[1][0]); }, {});
      PHASE(1, 3, { if (T + 3 < NT) SH(BgS, ldb, T + 3, 1, &Bs[1][0]); },
            { asm volatile("s_waitcnt vmcnt(4)" ::: "memory"); });
    }
  }
#undef PHASE

  // epilogue: C/D layout col=lane&15, row=(lane>>4)*4+reg  [m89/m91]
  char* Cb = (char*)Cv + (size_t)bzi * sCz * (OUTF ? 4 : 2);
  const long crow0 = bm + wm * 128 + fq * 4;
  const long ccol0 = bn + wn * 64 + fr;
#pragma unroll
  for (int i = 0; i < 8; ++i) {
#pragma unroll
    for (int j = 0; j < 4; ++j) {
      const long col = ccol0 + j * 16;
      float badd_c = (bias_mode == 1) ? bias[col] : 0.0f;
#pragma unroll
      for (int r = 0; r < 4; ++r) {
        const long row = crow0 + i * 16 + r;
        float v = acc[i][j][r] * alpha + badd_c;
        if (bias_mode == 2) v += bias[row];
        if (OUTF)
          ((float*)Cb)[row * ldc + col] = v;
        else
          ((unsigned short*)Cb)[row * ldc + col] = f2b(v);
      }
    }
  }
}

// ---------------------------------------------------------------------------
// In-place row softmax over bf16 rows of length 4096. One block (256thr)/row.
// ---------------------------------------------------------------------------
__global__ __launch_bounds__(256)
void softmax_rows(unsigned short* __restrict__ S) {
  const int t = threadIdx.x;
  unsigned short* row = S + (size_t)blockIdx.x * 4096;
  const bf16x8* p = (const bf16x8*)row;
  bf16x8 u0 = p[t * 2], u1 = p[t * 2 + 1];

  float v[16];
  float m = -1e30f;
#pragma unroll
  for (int j = 0; j < 8; j++) { v[j] = b2f((unsigned short)u0[j]); }
#pragma unroll
  for (int j = 0; j < 8; j++) { v[8 + j] = b2f((unsigned short)u1[j]); }
#pragma unroll
  for (int j = 0; j < 16; j++) m = fmaxf(m, v[j]);

#pragma unroll
  for (int off = 32; off > 0; off >>= 1) m = fmaxf(m, __shfl_xor(m, off));
  __shared__ float redm[4];
  if ((t & 63) == 0) redm[t >> 6] = m;
  __syncthreads();
  m = fmaxf(fmaxf(redm[0], redm[1]), fmaxf(redm[2], redm[3]));

  float s = 0.0f;
#pragma unroll
  for (int j = 0; j < 16; j++) { v[j] = __expf(v[j] - m); s += v[j]; }
#pragma unroll
  for (int off = 32; off > 0; off >>= 1) s += __shfl_xor(s, off);
  __shared__ float reds[4];
  if ((t & 63) == 0) reds[t >> 6] = s;
  __syncthreads();
  s = reds[0] + reds[1] + reds[2] + reds[3];
  const float inv = 1.0f / s;

  bf16x8 o0, o1;
#pragma unroll
  for (int j = 0; j < 8; j++) o0[j] = (short)f2b(v[j] * inv);
#pragma unroll
  for (int j = 0; j < 8; j++) o1[j] = (short)f2b(v[8 + j] * inv);
  bf16x8* q = (bf16x8*)row;
  q[t * 2] = o0;
  q[t * 2 + 1] = o1;
}

// ---------------------------------------------------------------------------
extern "C" void kernel_launch(void* const* d_in, const int* in_sizes, int n_in,
                              void* d_out, int out_size, void* d_ws,
                              size_t ws_size, hipStream_t stream) {
  const float* x  = (const float*)d_in[0];
  const float* Wq = (const float*)d_in[1];
  const float* bq = (const float*)d_in[2];
  const float* Wk = (const float*)d_in[3];
  const float* bk = (const float*)d_in[4];
  const float* Wv = (const float*)d_in[5];
  const float* bv = (const float*)d_in[6];
  float* out = (float*)d_out;

  const int Bb = 4, S = 4096, D = 1024;
  const long BS = (long)Bb * S;                 // 16384
  const size_t MiB = 1u << 20;

  char* base = (char*)d_ws;
  unsigned short* Wqt = (unsigned short*)(base);              // 2 MiB
  unsigned short* Wkt = (unsigned short*)(base + 2 * MiB);    // 2
  unsigned short* Wvt = (unsigned short*)(base + 4 * MiB);    // 2
  unsigned short* Qb  = (unsigned short*)(base + 6 * MiB);    // 32
  unsigned short* Kb  = (unsigned short*)(base + 38 * MiB);   // 32
  unsigned short* Vt  = (unsigned short*)(base + 70 * MiB);   // 32  [D][BS]
  unsigned short* xb  = (unsigned short*)(base + 102 * MiB);  // 32 (dies early)
  unsigned short* Sb  = xb;  // scores region overlaps dead xb
  const bool batched = ws_size >= (size_t)(102 + 128) * MiB;  // 4-batch scores

  // 1. x -> bf16
  const int n8 = (int)(BS * D / 8);
  convert_x<<<n8 / 256, 256, 0, stream>>>(x, xb, n8);

  // 2. W -> W^T bf16
  dim3 tb(32, 8), tg(32, 32);
  transpose_w<<<tg, tb, 0, stream>>>(Wq, Wqt);
  transpose_w<<<tg, tb, 0, stream>>>(Wk, Wkt);
  transpose_w<<<tg, tb, 0, stream>>>(Wv, Wvt);

  // 3. projections
  gemm256<0><<<dim3(D / 256, BS / 256, 1), 512, 0, stream>>>(
      xb, D, 0, Wqt, D, 0, Qb, D, 0, bq, 1, D, 1.0f);
  gemm256<0><<<dim3(D / 256, BS / 256, 1), 512, 0, stream>>>(
      xb, D, 0, Wkt, D, 0, Kb, D, 0, bk, 1, D, 1.0f);
  gemm256<0><<<dim3(BS / 256, D / 256, 1), 512, 0, stream>>>(
      Wvt, D, 0, xb, D, 0, Vt, BS, 0, bv, 2, D, 1.0f);

  // 4. attention
  const float scale = 0.03125f;  // 1/sqrt(1024)
  if (batched) {
    gemm256<0><<<dim3(S / 256, S / 256, Bb), 512, 0, stream>>>(
        Qb, D, (long)S * D, Kb, D, (long)S * D, Sb, S, (long)S * S,
        nullptr, 0, D, scale);
    softmax_rows<<<Bb * S, 256, 0, stream>>>(Sb);
    gemm256<1><<<dim3(D / 256, S / 256, Bb), 512, 0, stream>>>(
        Sb, S, (long)S * S, Vt, BS, (long)S, out, D, (long)S * D,
        nullptr, 0, S, 1.0f);
  } else {
    for (int b = 0; b < Bb; b++) {
      const unsigned short* Qp = Qb + (long)b * S * D;
      const unsigned short* Kp = Kb + (long)b * S * D;
      gemm256<0><<<dim3(S / 256, S / 256, 1), 512, 0, stream>>>(
          Qp, D, 0, Kp, D, 0, Sb, S, 0, nullptr, 0, D, scale);
      softmax_rows<<<S, 256, 0, stream>>>(Sb);
      gemm256<1><<<dim3(D / 256, S / 256, 1), 512, 0, stream>>>(
          Sb, S, 0, Vt + (long)b * S, BS, 0, out + (long)b * S * D, D, 0,
          nullptr, 0, S, 1.0f);
    }
  }
}